// Round 11
// baseline (362.275 us; speedup 1.0000x reference)
//
#include <hip/hip_runtime.h>
#include <hip/hip_bf16.h>
#include <math.h>

namespace {
constexpr int Bn = 2, Pn = 2048, On = 512, Dn = 256, Kn = 3, NREG = 2, Hn = 8, NL = 2;
constexpr int Ln = Pn + NREG + On - Kn;   // 2559
constexpr int Lpad = 2560;                // padded token count per (b,h)
constexpr int DH = 32;                    // head dim
constexpr int BH = Bn * Hn;               // 16
constexpr float EPS_COS = 1e-8f, EPS_LN = 1e-5f;
// 1/sqrt(32) * log2(e): QK^T lands in log2 domain -> bare v_exp_f32 (2^x)
constexpr float QS2 = 0.17677669529663687f * 1.4426950408889634f;

using bf16x8 = __attribute__((ext_vector_type(8))) short;
using f32x4  = __attribute__((ext_vector_type(4))) float;

union U8 { int4 i4; ushort u[8]; short s[8]; bf16x8 b; };
union U4 { uint2 i2; ushort u[4]; };

__device__ inline ushort f2bf(float f) {
  union { __bf16 h; ushort u; } c; c.h = (__bf16)f; return c.u;   // hw v_cvt (RNE)
}
__device__ inline float bf2f(ushort u) {
  union { unsigned u; float f; } c; c.u = (unsigned)u << 16; return c.f;
}

// bare v_exp_f32 (2^x). NOTE: "__exp2f" collides with a glibc math.h declaration.
__device__ inline float fexp2(float x) {
#if __has_builtin(__builtin_amdgcn_exp2f)
  return __builtin_amdgcn_exp2f(x);
#else
  float r;
  asm("v_exp_f32 %0, %1" : "=v"(r) : "v"(x));
  return r;
#endif
}

// DPP cross-lane (row of 16) reduction — VALU pipe, no LDS traffic.
template<int C> __device__ inline float dppf(float x) {
  return __builtin_bit_cast(float,
      __builtin_amdgcn_update_dpp(0, __builtin_bit_cast(int, x), C, 0xF, 0xF, false));
}
__device__ inline float red16_sum(float x) {
  x += dppf<0xB1>(x);
  x += dppf<0x4E>(x);
  x += dppf<0x124>(x);
  x += dppf<0x128>(x);
  return x;
}

// ---------- row-normalize xp/xo and split into bf16 hi/lo pairs ----------
// val = v / max(||row||, eps); hi = bf16(val); lo = bf16(val - hi).
// 3-term MFMA emulation error ~2^-18 * 16 terms ~ 2.4e-7 relative — ~400x
// below typical greedy-argmax gaps (~1e-4); selection preserved.
__global__ void k_rownorm(const float* __restrict__ xp, const float* __restrict__ xo,
                          ushort* __restrict__ xph, ushort* __restrict__ xpl,
                          ushort* __restrict__ xoh, ushort* __restrict__ xol) {
  int r = blockIdx.x;
  const float* src; ushort* dh; ushort* dl;
  if (r < Bn * Pn) {
    src = xp + (size_t)r * Dn; dh = xph + (size_t)r * Dn; dl = xpl + (size_t)r * Dn;
  } else {
    int r2 = r - Bn * Pn;
    src = xo + (size_t)r2 * Dn; dh = xoh + (size_t)r2 * Dn; dl = xol + (size_t)r2 * Dn;
  }
  int tid = threadIdx.x;
  float v = src[tid];
  float ss = v * v;
  #pragma unroll
  for (int m = 32; m >= 1; m >>= 1) ss += __shfl_xor(ss, m, 64);
  __shared__ float wsum[4];
  if ((tid & 63) == 0) wsum[tid >> 6] = ss;
  __syncthreads();
  float tot = wsum[0] + wsum[1] + wsum[2] + wsum[3];
  float val = v * (1.f / fmaxf(sqrtf(tot), EPS_COS));
  ushort hi = f2bf(val);
  dh[tid] = hi;
  dl[tid] = f2bf(val - bf2f(hi));
}

// ---------- sim GEMM via 3-term hi/lo bf16 MFMA: C = A @ B^T (f32 out) ----------
__global__ __launch_bounds__(64) void k_sim(
    const ushort* __restrict__ Ah, const ushort* __restrict__ Al,
    const ushort* __restrict__ Bh, const ushort* __restrict__ Bl,
    float* __restrict__ C)
{
  const int b = blockIdx.z;
  const int m0 = blockIdx.x * 32, n0 = blockIdx.y * 32;
  const int lane = threadIdx.x, lm = lane & 15, lh = lane >> 4;
  const ushort* ah = Ah + (size_t)b * Pn * 256;
  const ushort* al = Al + (size_t)b * Pn * 256;
  const ushort* bh = Bh + (size_t)b * On * 256;
  const ushort* bl = Bl + (size_t)b * On * 256;
  const size_t a0off = (size_t)(m0 + lm) * 256 + lh * 8;
  const size_t a1off = (size_t)(m0 + 16 + lm) * 256 + lh * 8;
  const size_t b0off = (size_t)(n0 + lm) * 256 + lh * 8;
  const size_t b1off = (size_t)(n0 + 16 + lm) * 256 + lh * 8;
  f32x4 acc[2][2] = {};
  #pragma unroll
  for (int k0 = 0; k0 < 256; k0 += 32) {
    U8 a0h, a0l, a1h, a1l, b0h, b0l, b1h, b1l;
    a0h.i4 = *(const int4*)(ah + a0off + k0);
    a0l.i4 = *(const int4*)(al + a0off + k0);
    a1h.i4 = *(const int4*)(ah + a1off + k0);
    a1l.i4 = *(const int4*)(al + a1off + k0);
    b0h.i4 = *(const int4*)(bh + b0off + k0);
    b0l.i4 = *(const int4*)(bl + b0off + k0);
    b1h.i4 = *(const int4*)(bh + b1off + k0);
    b1l.i4 = *(const int4*)(bl + b1off + k0);
    acc[0][0] = __builtin_amdgcn_mfma_f32_16x16x32_bf16(a0h.b, b0h.b, acc[0][0], 0, 0, 0);
    acc[0][1] = __builtin_amdgcn_mfma_f32_16x16x32_bf16(a0h.b, b1h.b, acc[0][1], 0, 0, 0);
    acc[1][0] = __builtin_amdgcn_mfma_f32_16x16x32_bf16(a1h.b, b0h.b, acc[1][0], 0, 0, 0);
    acc[1][1] = __builtin_amdgcn_mfma_f32_16x16x32_bf16(a1h.b, b1h.b, acc[1][1], 0, 0, 0);
    acc[0][0] = __builtin_amdgcn_mfma_f32_16x16x32_bf16(a0h.b, b0l.b, acc[0][0], 0, 0, 0);
    acc[0][1] = __builtin_amdgcn_mfma_f32_16x16x32_bf16(a0h.b, b1l.b, acc[0][1], 0, 0, 0);
    acc[1][0] = __builtin_amdgcn_mfma_f32_16x16x32_bf16(a1h.b, b0l.b, acc[1][0], 0, 0, 0);
    acc[1][1] = __builtin_amdgcn_mfma_f32_16x16x32_bf16(a1h.b, b1l.b, acc[1][1], 0, 0, 0);
    acc[0][0] = __builtin_amdgcn_mfma_f32_16x16x32_bf16(a0l.b, b0h.b, acc[0][0], 0, 0, 0);
    acc[0][1] = __builtin_amdgcn_mfma_f32_16x16x32_bf16(a0l.b, b1h.b, acc[0][1], 0, 0, 0);
    acc[1][0] = __builtin_amdgcn_mfma_f32_16x16x32_bf16(a1l.b, b0h.b, acc[1][0], 0, 0, 0);
    acc[1][1] = __builtin_amdgcn_mfma_f32_16x16x32_bf16(a1l.b, b1h.b, acc[1][1], 0, 0, 0);
  }
  float* Cb = C + (size_t)b * Pn * On;
  #pragma unroll
  for (int mi = 0; mi < 2; ++mi) {
    #pragma unroll
    for (int i = 0; i < 4; ++i) {
      int row = m0 + mi * 16 + lh * 4 + i;
      #pragma unroll
      for (int ni = 0; ni < 2; ++ni)
        Cb[(size_t)row * On + n0 + ni * 16 + lm] = acc[mi][ni][i];
    }
  }
}

// ---------- weight prep: W [z][Kd][N] f32 -> Wt [z][N][Kd] bf16 ----------
__global__ void k_wprep(const float* __restrict__ W, ushort* __restrict__ Wt, int Kd, int N) {
  const int z = blockIdx.z;
  const int n0 = blockIdx.x * 16, k0 = blockIdx.y * 16;
  const int tx = threadIdx.x & 15, ty = threadIdx.x >> 4;
  __shared__ float t[16][17];
  t[ty][tx] = W[(size_t)z * Kd * N + (size_t)(k0 + ty) * N + n0 + tx];
  __syncthreads();
  Wt[(size_t)z * Kd * N + (size_t)(n0 + ty) * Kd + k0 + tx] = f2bf(t[tx][ty]);
}

// ---------- QKV GEMM 32x64/wave: A(bf16 Mx256) @ WqkvT -> bf16 Qh/Kh/Vtg ----------
__global__ __launch_bounds__(64) void k_gemm_qkv(
    const ushort* __restrict__ A, const ushort* __restrict__ Bt,
    const float* __restrict__ bias,
    ushort* __restrict__ Qh, ushort* __restrict__ Kh, ushort* __restrict__ Vtg, int M)
{
  const int m0 = blockIdx.x * 32, n0 = blockIdx.y * 64;
  const int lane = threadIdx.x, lm = lane & 15, lh = lane >> 4;
  f32x4 acc[2][4] = {};
  int rA[2];
  #pragma unroll
  for (int mi = 0; mi < 2; ++mi) { int r = m0 + mi * 16 + lm; rA[mi] = r < M ? r : M - 1; }
  const ushort* bp0 = Bt + (size_t)(n0 +  0 + lm) * 256 + lh * 8;
  const ushort* bp1 = Bt + (size_t)(n0 + 16 + lm) * 256 + lh * 8;
  const ushort* bp2 = Bt + (size_t)(n0 + 32 + lm) * 256 + lh * 8;
  const ushort* bp3 = Bt + (size_t)(n0 + 48 + lm) * 256 + lh * 8;
  #pragma unroll
  for (int k0 = 0; k0 < 256; k0 += 32) {
    U8 a0, a1, b0, b1, b2, b3;
    a0.i4 = *(const int4*)(A + (size_t)rA[0] * 256 + k0 + lh * 8);
    a1.i4 = *(const int4*)(A + (size_t)rA[1] * 256 + k0 + lh * 8);
    b0.i4 = *(const int4*)(bp0 + k0);
    b1.i4 = *(const int4*)(bp1 + k0);
    b2.i4 = *(const int4*)(bp2 + k0);
    b3.i4 = *(const int4*)(bp3 + k0);
    acc[0][0] = __builtin_amdgcn_mfma_f32_16x16x32_bf16(a0.b, b0.b, acc[0][0], 0, 0, 0);
    acc[0][1] = __builtin_amdgcn_mfma_f32_16x16x32_bf16(a0.b, b1.b, acc[0][1], 0, 0, 0);
    acc[0][2] = __builtin_amdgcn_mfma_f32_16x16x32_bf16(a0.b, b2.b, acc[0][2], 0, 0, 0);
    acc[0][3] = __builtin_amdgcn_mfma_f32_16x16x32_bf16(a0.b, b3.b, acc[0][3], 0, 0, 0);
    acc[1][0] = __builtin_amdgcn_mfma_f32_16x16x32_bf16(a1.b, b0.b, acc[1][0], 0, 0, 0);
    acc[1][1] = __builtin_amdgcn_mfma_f32_16x16x32_bf16(a1.b, b1.b, acc[1][1], 0, 0, 0);
    acc[1][2] = __builtin_amdgcn_mfma_f32_16x16x32_bf16(a1.b, b2.b, acc[1][2], 0, 0, 0);
    acc[1][3] = __builtin_amdgcn_mfma_f32_16x16x32_bf16(a1.b, b3.b, acc[1][3], 0, 0, 0);
  }
  const int typ = n0 >> 8;             // 0=Q, 1=K, 2=V (64-tile never crosses)
  #pragma unroll
  for (int g = 0; g < 4; ++g) {
    const int hh = ((n0 & 255) + 16 * g) >> 5;
    const int dcol = (16 * g + lm) & 31;
    const float bv = bias[n0 + 16 * g + lm];
    #pragma unroll
    for (int mi = 0; mi < 2; ++mi) {
      #pragma unroll
      for (int i = 0; i < 4; ++i) {
        int row = m0 + mi * 16 + lh * 4 + i;
        if (row >= M) continue;
        int b = (row >= Ln) ? 1 : 0;
        int t = row - b * Ln;
        float v = acc[mi][g][i] + bv;
        size_t bhh = (size_t)(b * Hn + hh);
        if (typ == 0) {
          Qh[(bhh * Lpad + t) * 32 + dcol] = f2bf(v * QS2);
        } else if (typ == 1) {
          Kh[(bhh * Lpad + t) * 32 + dcol] = f2bf(v);
        } else {
          // permuted k-slot order matching flash's P layout: slot = (t&15)*4 + ((t>>4)&3)
          int tp = (t & ~63) | ((t & 15) << 2) | ((t >> 4) & 3);
          Vtg[bhh * (size_t)(32 * Lpad) + (size_t)dcol * Lpad + tp] = f2bf(v);
        }
      }
    }
  }
}

// ---------- out-proj GEMM 32x32/wave: C(f32)=A@Bt^T + bias + resid ----------
template<bool LAST>
__global__ __launch_bounds__(64) void k_gemm_out(
    const ushort* __restrict__ A, const ushort* __restrict__ Bt,
    const float* __restrict__ bias, const float* __restrict__ resid,
    float* __restrict__ C, float* __restrict__ outp, int M, int N)
{
  const int m0 = blockIdx.x * 32, n0 = blockIdx.y * 32;
  const int lane = threadIdx.x, lm = lane & 15, lh = lane >> 4;
  f32x4 acc[2][2] = {};
  int rA[2];
  #pragma unroll
  for (int mi = 0; mi < 2; ++mi) { int r = m0 + mi * 16 + lm; rA[mi] = r < M ? r : M - 1; }
  const ushort* bp0 = Bt + (size_t)(n0 + lm) * 256 + lh * 8;
  const ushort* bp1 = Bt + (size_t)(n0 + 16 + lm) * 256 + lh * 8;
  #pragma unroll
  for (int k0 = 0; k0 < 256; k0 += 32) {
    U8 a0, a1, bb0, bb1;
    a0.i4 = *(const int4*)(A + (size_t)rA[0] * 256 + k0 + lh * 8);
    a1.i4 = *(const int4*)(A + (size_t)rA[1] * 256 + k0 + lh * 8);
    bb0.i4 = *(const int4*)(bp0 + k0);
    bb1.i4 = *(const int4*)(bp1 + k0);
    acc[0][0] = __builtin_amdgcn_mfma_f32_16x16x32_bf16(a0.b, bb0.b, acc[0][0], 0, 0, 0);
    acc[0][1] = __builtin_amdgcn_mfma_f32_16x16x32_bf16(a0.b, bb1.b, acc[0][1], 0, 0, 0);
    acc[1][0] = __builtin_amdgcn_mfma_f32_16x16x32_bf16(a1.b, bb0.b, acc[1][0], 0, 0, 0);
    acc[1][1] = __builtin_amdgcn_mfma_f32_16x16x32_bf16(a1.b, bb1.b, acc[1][1], 0, 0, 0);
  }
  const float bv0 = bias[n0 + lm], bv1 = bias[n0 + 16 + lm];
  #pragma unroll
  for (int mi = 0; mi < 2; ++mi) {
    #pragma unroll
    for (int i = 0; i < 4; ++i) {
      int row = m0 + mi * 16 + lh * 4 + i;
      if (row >= M) continue;
      float v0 = acc[mi][0][i] + bv0 + resid[(size_t)row * N + n0 + lm];
      float v1 = acc[mi][1][i] + bv1 + resid[(size_t)row * N + n0 + 16 + lm];
      if (!LAST) {
        C[(size_t)row * N + n0 + lm] = v0;
        C[(size_t)row * N + n0 + 16 + lm] = v1;
      } else {
        int b = (row >= Ln) ? 1 : 0;
        int t = row - b * Ln;
        size_t off;
        if (t == 0) off = (size_t)b * Dn;
        else if (t < Pn) off = (size_t)Bn * Dn + ((size_t)b * (Pn - 1) + (t - 1)) * Dn;
        else if (t < Pn + NREG) continue;          // bottleneck tokens not output
        else if (t == Pn + NREG) off = (size_t)Bn * Dn + (size_t)Bn * (Pn - 1) * Dn + (size_t)b * Dn;
        else off = (size_t)Bn * Dn * 2 + (size_t)Bn * (Pn - 1) * Dn +
                   ((size_t)b * (On - Kn - 1) + (t - (Pn + NREG + 1))) * Dn;
        outp[off + n0 + lm] = v0;
        outp[off + n0 + 16 + lm] = v1;
      }
    }
  }
}

// ---------- per-row top-3 (distinct columns) of sim; 1 wave/row ----------
__global__ __launch_bounds__(64) void k_top3(const float* __restrict__ sim,
                                             float* __restrict__ t3v, int* __restrict__ t3c) {
  const int row = blockIdx.x, lane = threadIdx.x;
  const float* rp = sim + (size_t)row * On + lane * 8;
  float4 va = *(const float4*)rp, vb2 = *(const float4*)(rp + 4);
  float v[8] = { va.x, va.y, va.z, va.w, vb2.x, vb2.y, vb2.z, vb2.w };
  int ex = 0;
  for (int s = 0; s < 3; ++s) {
    float bv = -INFINITY; int bi = 1 << 30;
    #pragma unroll
    for (int j = 0; j < 8; ++j) {
      int idx = lane * 8 + j;
      bool ok = !((ex >> j) & 1);
      if (ok && (v[j] > bv || (v[j] == bv && idx < bi))) { bv = v[j]; bi = idx; }
    }
    #pragma unroll
    for (int m = 1; m < 64; m <<= 1) {
      float ov = __shfl_xor(bv, m, 64); int oi = __shfl_xor(bi, m, 64);
      if (ov > bv || (ov == bv && oi < bi)) { bv = ov; bi = oi; }
    }
    if (lane == 0) { t3v[(size_t)row * 3 + s] = bv; t3c[(size_t)row * 3 + s] = bi; }
    if ((bi >> 3) == lane) ex |= 1 << (bi & 7);
  }
}

// ---------- sequential greedy K=3 over per-row top-3 candidates (1024 thr) ----------
__global__ __launch_bounds__(1024) void k_greedy(const float* __restrict__ t3v,
                                                 const int* __restrict__ t3c, int* __restrict__ sel) {
  const int b = blockIdx.x, tid = threadIdx.x;
  __shared__ float redv[1024];
  __shared__ long long redi[1024];
  __shared__ int selp[3], selc[3];
  const float* tv = t3v + (size_t)b * Pn * 3;
  const int*   tc = t3c + (size_t)b * Pn * 3;
  for (int s = 0; s < 3; ++s) {
    float bvv = -INFINITY; long long bi = 0x7fffffffffffffffLL;
    for (int p = tid; p < Pn; p += 1024) {
      bool used = false;
      for (int u = 0; u < s; ++u) used |= (selp[u] == p);
      if (used) continue;
      #pragma unroll
      for (int j = 0; j < 3; ++j) {
        int cc = tc[p * 3 + j];
        bool cused = false;
        for (int u = 0; u < s; ++u) cused |= (selc[u] == cc);
        if (cused) continue;
        float vv = tv[p * 3 + j];
        long long fi = (long long)p * On + cc;
        if (vv > bvv || (vv == bvv && fi < bi)) { bvv = vv; bi = fi; }
      }
    }
    redv[tid] = bvv; redi[tid] = bi;
    __syncthreads();
    for (int off = 512; off; off >>= 1) {
      if (tid < off) {
        if (redv[tid + off] > redv[tid] ||
            (redv[tid + off] == redv[tid] && redi[tid + off] < redi[tid])) {
          redv[tid] = redv[tid + off]; redi[tid] = redi[tid + off];
        }
      }
      __syncthreads();
    }
    if (tid == 0) { selp[s] = (int)(redi[0] / On); selc[s] = (int)(redi[0] % On); }
    __syncthreads();
  }
  if (tid == 0) {
    int* o = sel + b * 12;
    int sp0 = selp[0], sp1 = selp[1], sp2 = selp[2];
    int sc0 = selc[0], sc1 = selc[1], sc2 = selc[2];
    o[0] = sp0; o[1] = sp1; o[2] = sp2; o[3] = sc0; o[4] = sc1; o[5] = sc2;
    int t;
    if (sp0 > sp1) { t = sp0; sp0 = sp1; sp1 = t; }
    if (sp1 > sp2) { t = sp1; sp1 = sp2; sp2 = t; }
    if (sp0 > sp1) { t = sp0; sp0 = sp1; sp1 = t; }
    if (sc0 > sc1) { t = sc0; sc0 = sc1; sc1 = t; }
    if (sc1 > sc2) { t = sc1; sc1 = sc2; sc2 = t; }
    if (sc0 > sc1) { t = sc0; sc0 = sc1; sc1 = t; }
    o[6] = sp0; o[7] = sp1; o[8] = sp2; o[9] = sc0; o[10] = sc1; o[11] = sc2;
  }
}

// ---------- LN helper (256-thread block over one row) ----------
__device__ inline void ln_write(float v, const float* __restrict__ g,
                                const float* __restrict__ bb, ushort* __restrict__ dst,
                                int tid) {
  float s = v;
  #pragma unroll
  for (int m = 32; m >= 1; m >>= 1) s += __shfl_xor(s, m, 64);
  __shared__ float w1[4], w2[4];
  if ((tid & 63) == 0) w1[tid >> 6] = s;
  __syncthreads();
  float mu = (w1[0] + w1[1] + w1[2] + w1[3]) * (1.f / Dn);
  float d = v - mu;
  float q = d * d;
  #pragma unroll
  for (int m = 32; m >= 1; m >>= 1) q += __shfl_xor(q, m, 64);
  if ((tid & 63) == 0) w2[tid >> 6] = q;
  __syncthreads();
  float var = (w2[0] + w2[1] + w2[2] + w2[3]) * (1.f / Dn);
  dst[tid] = f2bf(d * rsqrtf(var + EPS_LN) * g[tid] + bb[tid]);
}

// ---------- pair tokens + layer-0 LN ----------
__global__ void k_pair_ln(const float* __restrict__ xp, const float* __restrict__ xo,
                          const float* __restrict__ Wlp, const float* __restrict__ blp,
                          const float* __restrict__ Wlo, const float* __restrict__ blo,
                          const int* __restrict__ sel, const float* __restrict__ g,
                          const float* __restrict__ bb,
                          float* __restrict__ x, ushort* __restrict__ xnb) {
  const int k = blockIdx.x, b = blockIdx.y, d = threadIdx.x;
  const int ip = sel[b * 12 + k], io = sel[b * 12 + 3 + k];
  const float* xpr = xp + ((size_t)b * Pn + ip) * Dn;
  const float* xom = xo + ((size_t)b * On + io) * Dn;
  float acc = blp[d] + blo[d];
  for (int i = 0; i < Dn; ++i)
    acc += xpr[i] * Wlp[(size_t)i * Dn + d] + xom[i] * Wlo[(size_t)i * Dn + d];
  const size_t row = (size_t)b * Ln + k;
  x[row * Dn + d] = acc;
  ln_write(acc, g, bb, xnb + row * Dn, d);
}

// ---------- gather remaining rows + bottleneck tokens + layer-0 LN ----------
__global__ void k_gather_ln(const float* __restrict__ xp, const float* __restrict__ xo,
                            const float* __restrict__ bottle, const int* __restrict__ sel,
                            const float* __restrict__ g, const float* __restrict__ bb,
                            float* __restrict__ x, ushort* __restrict__ xnb) {
  const int idx = blockIdx.x;
  const int b = idx / Ln, t = idx % Ln;
  if (t < Kn) return;                    // handled by k_pair_ln
  const float* src;
  if (t < Pn) {
    const int* rp = sel + b * 12 + 6;
    int s2 = t - Kn;
    if (s2 >= rp[0]) s2++;
    if (s2 >= rp[1]) s2++;
    if (s2 >= rp[2]) s2++;
    src = xp + ((size_t)b * Pn + s2) * Dn;
  } else if (t < Pn + NREG) {
    src = bottle + (size_t)(t - Pn) * Dn;
  } else {
    const int* ro = sel + b * 12 + 9;
    int s2 = t - (Pn + NREG);
    if (s2 >= ro[0]) s2++;
    if (s2 >= ro[1]) s2++;
    if (s2 >= ro[2]) s2++;
    src = xo + ((size_t)b * On + s2) * Dn;
  }
  float v = src[threadIdx.x];
  x[(size_t)idx * Dn + threadIdx.x] = v;
  ln_write(v, g, bb, xnb + (size_t)idx * Dn, threadIdx.x);
}

// ---------- LayerNorm per token -> bf16 (layers >= 1) ----------
__global__ void k_ln(const float* __restrict__ x, const float* __restrict__ g,
                     const float* __restrict__ bb, ushort* __restrict__ xnb) {
  const size_t row = blockIdx.x;
  const int tid = threadIdx.x;
  ln_write(x[row * Dn + tid], g, bb, xnb + row * Dn, tid);
}

// ---------- flash attention, 2-way K-split, fixed-max softmax, NO BARRIERS ----------
// K/V fragments load DIRECTLY from global (L2-resident: 164 KB per (b,h), shared
// by all 160 blocks of that head). Kh head-major makes K-frag loads contiguous;
// Vtg's permuted k-slot layout makes V-frag loads 16B-contiguous per lane.
// LDS holds only the wave-private P transpose -> zero __syncthreads in the loop.
__global__ __launch_bounds__(128) void k_flash_mfma(const ushort* __restrict__ Qh,
                                                    const ushort* __restrict__ Kh,
                                                    const ushort* __restrict__ Vtg,
                                                    float* __restrict__ Opart,
                                                    float* __restrict__ lpart) {
  const int qt = blockIdx.x, h = blockIdx.y;
  const int bz = blockIdx.z, b = bz >> 1, sp = bz & 1;
  const int q0 = qt * 32;
  const int tid = threadIdx.x;
  const int w = tid >> 6, lane = tid & 63;
  const int lm = lane & 15, lh = lane >> 4;
  __shared__ __attribute__((aligned(16))) short Ps[2][1024];  // per-wave 16x64, swizzled
  const int bh = b * Hn + h;
  const ushort* Qg = Qh + (size_t)bh * Lpad * 32;
  const ushort* Kg = Kh + (size_t)bh * Lpad * 32 + (size_t)sp * 1280 * 32;
  const ushort* Vg = Vtg + (size_t)bh * (32 * Lpad) + (size_t)sp * 1280;
  U8 aq;
  aq.i4 = *(const int4*)(Qg + (size_t)(q0 + w * 16 + lm) * 32 + lh * 8);
  float lsum[4] = {0.f, 0.f, 0.f, 0.f};
  f32x4 O0 = {0.f, 0.f, 0.f, 0.f}, O1 = {0.f, 0.f, 0.f, 0.f};
  const f32x4 zacc = {0.f, 0.f, 0.f, 0.f};
  // per-lane fragment base pointers (advance by k0 each chunk)
  const ushort* kfp = Kg + (size_t)lm * 32 + lh * 8;          // + (k0 + g*16)*32
  const ushort* vf00 = Vg + (size_t)lm * Lpad + lh * 8;       // + k0
  const ushort* vf01 = Vg + (size_t)(16 + lm) * Lpad + lh * 8;
  const int NTL = 20;                                  // 20 chunks per split
  for (int kt = 0; kt < NTL; ++kt) {
    const int k0 = kt * 64;                 // local key base within split
    // QK^T: K fragments direct from global (contiguous 1KB per frag per wave)
    U8 b0, b1, b2, b3;
    b0.i4 = *(const int4*)(kfp + (size_t)(k0 +  0) * 32);
    b1.i4 = *(const int4*)(kfp + (size_t)(k0 + 16) * 32);
    b2.i4 = *(const int4*)(kfp + (size_t)(k0 + 32) * 32);
    b3.i4 = *(const int4*)(kfp + (size_t)(k0 + 48) * 32);
    f32x4 S0 = __builtin_amdgcn_mfma_f32_16x16x32_bf16(aq.b, b0.b, zacc, 0, 0, 0);
    f32x4 S1 = __builtin_amdgcn_mfma_f32_16x16x32_bf16(aq.b, b1.b, zacc, 0, 0, 0);
    f32x4 S2 = __builtin_amdgcn_mfma_f32_16x16x32_bf16(aq.b, b2.b, zacc, 0, 0, 0);
    f32x4 S3 = __builtin_amdgcn_mfma_f32_16x16x32_bf16(aq.b, b3.b, zacc, 0, 0, 0);
    const int kg = sp * 1280 + k0;          // global key base of this chunk
    const bool tail = (kg + 64 > Ln);
    #pragma unroll
    for (int i = 0; i < 4; ++i) {
      float v0 = S0[i], v1 = S1[i], v2 = S2[i], v3 = S3[i];
      if (tail) {
        v0 = (kg +  0 + lm < Ln) ? v0 : -INFINITY;
        v1 = (kg + 16 + lm < Ln) ? v1 : -INFINITY;
        v2 = (kg + 32 + lm < Ln) ? v2 : -INFINITY;
        v3 = (kg + 48 + lm < Ln) ? v3 : -INFINITY;
      }
      float p0 = fexp2(v0), p1 = fexp2(v1);
      float p2 = fexp2(v2), p3 = fexp2(v3);
      lsum[i] += (p0 + p1) + (p2 + p3);     // per-lane partial; DPP-reduce after loop
      U4 pw;
      pw.u[0] = f2bf(p0); pw.u[1] = f2bf(p1); pw.u[2] = f2bf(p2); pw.u[3] = f2bf(p3);
      const int r = lh * 4 + i;
      const int idxw = (r * 64 + lm * 4) ^ ((r & 7) << 3);
      *(uint2*)&Ps[w][idxw] = pw.i2;
    }
    // PV: P via wave-private LDS transpose (in-order, no sync); V direct from global
    U8 pa0, pa1, v00, v01, v10, v11;
    {
      const int ra = lm * 64, sw = (lm & 7) << 3;
      pa0.i4 = *(const int4*)&Ps[w][(ra +      lh * 8) ^ sw];
      pa1.i4 = *(const int4*)&Ps[w][(ra + 32 + lh * 8) ^ sw];
    }
    v00.i4 = *(const int4*)(vf00 + k0);
    v01.i4 = *(const int4*)(vf01 + k0);
    v10.i4 = *(const int4*)(vf00 + k0 + 32);
    v11.i4 = *(const int4*)(vf01 + k0 + 32);
    O0 = __builtin_amdgcn_mfma_f32_16x16x32_bf16(pa0.b, v00.b, O0, 0, 0, 0);
    O0 = __builtin_amdgcn_mfma_f32_16x16x32_bf16(pa1.b, v10.b, O0, 0, 0, 0);
    O1 = __builtin_amdgcn_mfma_f32_16x16x32_bf16(pa0.b, v01.b, O1, 0, 0, 0);
    O1 = __builtin_amdgcn_mfma_f32_16x16x32_bf16(pa1.b, v11.b, O1, 0, 0, 0);
  }
  // epilogue: partial O (f32) and l per split
  #pragma unroll
  for (int i = 0; i < 4; ++i) {
    float lred = red16_sum(lsum[i]);
    int grow = q0 + w * 16 + lh * 4 + i;
    if (grow < Ln) {
      float* op = Opart + ((size_t)(sp * BH + bh) * Lpad + grow) * 32;
      op[lm]      = O0[i];
      op[16 + lm] = O1[i];
      if (lm == 0) lpart[(size_t)(sp * BH + bh) * Lpad + grow] = lred;
    }
  }
}

// ---------- combine split partials: attnb = (O0+O1)/(l0+l1), bf16 ----------
__global__ __launch_bounds__(256) void k_combine(const float* __restrict__ Opart,
                                                 const float* __restrict__ lpart,
                                                 ushort* __restrict__ attnb) {
  const int idx = blockIdx.x * 256 + threadIdx.x;    // [0, BH*Ln*32)
  const int d = idx & 31;
  const int rest = idx >> 5;                         // bh*Ln + q
  const int bh = rest / Ln;
  const int q = rest - bh * Ln;
  const float o = Opart[((size_t)bh * Lpad + q) * 32 + d] +
                  Opart[((size_t)(BH + bh) * Lpad + q) * 32 + d];
  const float l = lpart[(size_t)bh * Lpad + q] +
                  lpart[(size_t)(BH + bh) * Lpad + q];
  const int b = bh >> 3, h = bh & 7;
  attnb[((size_t)b * Ln + q) * Dn + h * 32 + d] = f2bf(o / l);
}

} // anonymous namespace

extern "C" void kernel_launch(void* const* d_in, const int* in_sizes, int n_in,
                              void* d_out, int out_size, void* d_ws, size_t ws_size,
                              hipStream_t stream) {
  const float* x_path = (const float*)d_in[0];
  const float* x_omic = (const float*)d_in[1];
  const float* bottle = (const float*)d_in[2];
  const float* Wlp    = (const float*)d_in[3];
  const float* blp    = (const float*)d_in[4];
  const float* Wlo    = (const float*)d_in[5];
  const float* blo    = (const float*)d_in[6];
  const float* ln_g   = (const float*)d_in[7];
  const float* ln_b   = (const float*)d_in[8];
  const float* Wqkv   = (const float*)d_in[9];
  const float* bqkv   = (const float*)d_in[10];
  const float* Wo     = (const float*)d_in[11];
  const float* bo     = (const float*)d_in[12];
  float* out = (float*)d_out;

  // workspace layout (256B-aligned chunks)
  char* base = (char*)d_ws;
  auto alloc = [&](size_t bytes) { char* p = base; base += (bytes + 255) & ~(size_t)255; return p; };
  int*    sel    = (int*)alloc(256);
  float*  x      = (float*)alloc(sizeof(float) * Bn * Ln * Dn);
  ushort* xnb    = (ushort*)alloc(sizeof(ushort) * Bn * Ln * Dn);
  ushort* attnb  = (ushort*)alloc(sizeof(ushort) * Bn * Ln * Dn);
  ushort* Qh     = (ushort*)alloc(sizeof(ushort) * Bn * Hn * Lpad * 32);
  ushort* Kh     = (ushort*)alloc(sizeof(ushort) * Bn * Hn * Lpad * 32);
  ushort* Vtg    = (ushort*)alloc(sizeof(ushort) * Bn * Hn * 32 * Lpad);
  ushort* WqkvT  = (ushort*)alloc(sizeof(ushort) * NL * Dn * 3 * Dn);
  ushort* WoT    = (ushort*)alloc(sizeof(ushort) * NL * Dn * Dn);
  ushort* xph    = (ushort*)alloc(sizeof(ushort) * Bn * Pn * Dn);
  ushort* xpl    = (ushort*)alloc(sizeof(ushort) * Bn * Pn * Dn);
  ushort* xoh    = (ushort*)alloc(sizeof(ushort) * Bn * On * Dn);
  ushort* xol    = (ushort*)alloc(sizeof(ushort) * Bn * On * Dn);
  float*  simb   = (float*)alloc(sizeof(float) * Bn * Pn * On);
  float*  t3v    = (float*)alloc(sizeof(float) * Bn * Pn * 3);
  int*    t3c    = (int*)alloc(sizeof(int) * Bn * Pn * 3);
  float*  Opart  = (float*)alloc(sizeof(float) * 2 * BH * Lpad * 32);
  float*  lpart  = (float*)alloc(sizeof(float) * 2 * BH * Lpad);

  // weight prep (bf16, transposed)
  k_wprep<<<dim3(768 / 16, 256 / 16, NL), 256, 0, stream>>>(Wqkv, WqkvT, 256, 768);
  k_wprep<<<dim3(256 / 16, 256 / 16, NL), 256, 0, stream>>>(Wo, WoT, 256, 256);

  // assembly phase (hi/lo bf16 MFMA sim; selection margin analysis in k_rownorm)
  k_rownorm<<<Bn * (Pn + On), 256, 0, stream>>>(x_path, x_omic, xph, xpl, xoh, xol);
  k_sim<<<dim3(Pn / 32, On / 32, Bn), 64, 0, stream>>>(xph, xpl, xoh, xol, simb);
  k_top3<<<Bn * Pn, 64, 0, stream>>>(simb, t3v, t3c);
  k_greedy<<<Bn, 1024, 0, stream>>>(t3v, t3c, sel);
  k_pair_ln<<<dim3(Kn, Bn), 256, 0, stream>>>(x_path, x_omic, Wlp, blp, Wlo, blo, sel,
                                              ln_g, ln_b, x, xnb);
  k_gather_ln<<<Bn * Ln, 256, 0, stream>>>(x_path, x_omic, bottle, sel, ln_g, ln_b, x, xnb);

  const int Mrows = Bn * Ln;                 // 5118
  const int mt32 = (Mrows + 31) / 32;        // 160
  const int cgrid = (BH * Ln * 32) / 256;    // 5118 (exact)
  // layer 0
  k_gemm_qkv<<<dim3(mt32, 12), 64, 0, stream>>>(xnb, WqkvT, bqkv, Qh, Kh, Vtg, Mrows);
  k_flash_mfma<<<dim3(80, Hn, Bn * 2), 128, 0, stream>>>(Qh, Kh, Vtg, Opart, lpart);
  k_combine<<<cgrid, 256, 0, stream>>>(Opart, lpart, attnb);
  k_gemm_out<false><<<dim3(mt32, 8), 64, 0, stream>>>(attnb, WoT, bo, x, x, nullptr, Mrows, Dn);
  // layer 1
  k_ln<<<Mrows, 256, 0, stream>>>(x, ln_g + Dn, ln_b + Dn, xnb);
  k_gemm_qkv<<<dim3(mt32, 12), 64, 0, stream>>>(xnb, WqkvT + (size_t)Dn * 3 * Dn,
                                                bqkv + 3 * Dn, Qh, Kh, Vtg, Mrows);
  k_flash_mfma<<<dim3(80, Hn, Bn * 2), 128, 0, stream>>>(Qh, Kh, Vtg, Opart, lpart);
  k_combine<<<cgrid, 256, 0, stream>>>(Opart, lpart, attnb);
  k_gemm_out<true><<<dim3(mt32, 8), 64, 0, stream>>>(attnb, WoT + (size_t)Dn * Dn,
                                                     bo + Dn, x, nullptr, out, Mrows, Dn);
}